// Round 1
// baseline (265.386 us; speedup 1.0000x reference)
//
#include <hip/hip_runtime.h>

#define GLOBAL_AS __attribute__((address_space(1)))
#define LDS_AS __attribute__((address_space(3)))

typedef _Float16 half_t;
typedef _Float16 f16x8 __attribute__((ext_vector_type(8)));
typedef float f32x4 __attribute__((ext_vector_type(4)));

static constexpr int BATCH = 8;
static constexpr int CH = 256;
static constexpr int N = 2304;     // 48*48
static constexpr int KTOT = 4096;  // 2 * BATCH * CH (G1 and G2 fused along K)
static constexpr float EPS = 1e-8f;
static constexpr float THR = 31.5f;

// ws layout:
//   [0,4)        float   s accumulator
//   [4,8)        uint    mask count
//   [256, +294912)  float scales[4][8][2304]  (tensor order = d_in order y,yp,z,zp)
//   At = ws + 295168            : half [2304][4096]  rows = n, k-contiguous ([yhat; zhat])
//   Bt = At + 18874368 bytes    : half [2304][4096]  rows = m, k-contiguous ([zphat; yphat])
// total ~38.04 MB

// ---------------- 1. per-(tensor,b,n) inverse norms ----------------
__global__ void norms_kernel(const float* __restrict__ y, const float* __restrict__ yp,
                             const float* __restrict__ z, const float* __restrict__ zp,
                             float* __restrict__ scales) {
  const int n = blockIdx.x * 256 + threadIdx.x;  // 9*256 = 2304
  const int b = blockIdx.y;
  const int t = blockIdx.z;
  const float* src = (t == 0) ? y : (t == 1) ? yp : (t == 2) ? z : zp;
  const float* p = src + (size_t)(b * CH) * N + n;
  float ss = 0.f;
#pragma unroll 8
  for (int c = 0; c < CH; ++c) {
    float v = p[(size_t)c * N];
    ss = fmaf(v, v, ss);
  }
  float nrm = fmaxf(sqrtf(ss), EPS);
  scales[((size_t)t * BATCH + b) * N + n] = 1.0f / nrm;
}

// ---------------- 2. normalize + transpose to [n][k] fp16 ----------------
// bz: 0: y -> At k<2048 | 1: z -> At k>=2048 | 2: zp -> Bt k<2048 | 3: yp -> Bt k>=2048
__global__ void pack_kernel(const float* __restrict__ y, const float* __restrict__ yp,
                            const float* __restrict__ z, const float* __restrict__ zp,
                            const float* __restrict__ scales,
                            half_t* __restrict__ At, half_t* __restrict__ Bt) {
  const int bz = blockIdx.z;
  const int b  = blockIdx.y >> 2;
  const int ct = blockIdx.y & 3;   // 64-wide c tile
  const int n0 = blockIdx.x * 64;  // 36*64 = 2304
  const float* src; int sidx; half_t* dst;
  switch (bz) {
    case 0:  src = y;  sidx = 0; dst = At; break;
    case 1:  src = z;  sidx = 2; dst = At; break;
    case 2:  src = zp; sidx = 3; dst = Bt; break;
    default: src = yp; sidx = 1; dst = Bt; break;
  }
  const int kb = ((bz & 1) ? 2048 : 0) + b * 256 + ct * 64;

  __shared__ float tile[64][65];  // [c][n], +1 pad
  const int t = threadIdx.x;
  {
    const int col = (t & 15) * 4;
    const int cb  = t >> 4;
#pragma unroll
    for (int r = 0; r < 4; ++r) {
      const int cc = r * 16 + cb;
      const float4 v = *(const float4*)(src + (size_t)(b * CH + ct * 64 + cc) * N + n0 + col);
      tile[cc][col] = v.x; tile[cc][col + 1] = v.y;
      tile[cc][col + 2] = v.z; tile[cc][col + 3] = v.w;
    }
  }
  __syncthreads();
  const int nn = t >> 2, cseg = t & 3;
  const float sc = scales[((size_t)sidx * BATCH + b) * N + n0 + nn];
  union { half_t h[16]; f16x8 v[2]; } u;
#pragma unroll
  for (int i = 0; i < 16; ++i)
    u.h[i] = (half_t)(tile[cseg * 16 + i][nn] * sc);
  f16x8* dp = (f16x8*)(dst + (size_t)(n0 + nn) * KTOT + kb + cseg * 16);
  dp[0] = u.v[0];
  dp[1] = u.v[1];
}

// ---------------- 3. mask count ----------------
__global__ void count_kernel(const float* __restrict__ dist, unsigned int* __restrict__ cnt) {
  const size_t i0 = ((size_t)blockIdx.x * 256 + threadIdx.x) * 8;  // 2592 blocks * 2048
  const float4* p = (const float4*)(dist + i0);
  float4 a = p[0], b = p[1];
  int c = (a.x < THR) + (a.y < THR) + (a.z < THR) + (a.w < THR)
        + (b.x < THR) + (b.y < THR) + (b.z < THR) + (b.w < THR);
#pragma unroll
  for (int off = 32; off; off >>= 1) c += __shfl_down(c, off, 64);
  __shared__ int red[4];
  if ((threadIdx.x & 63) == 0) red[threadIdx.x >> 6] = c;
  __syncthreads();
  if (threadIdx.x == 0)
    atomicAdd(cnt, (unsigned int)(red[0] + red[1] + red[2] + red[3]));
}

// ---------------- 4. GEMM s += sum_mask (At * Bt^T) ----------------
// G[n][m] = sum_k At[n][k]*Bt[m][k]; 128x128 tile, BK=32, K-split z=4.
__global__ __launch_bounds__(256) void gemm_kernel(
    const half_t* __restrict__ At, const half_t* __restrict__ Bt,
    const float* __restrict__ dist, float* __restrict__ s_out) {
  __shared__ half_t As[128 * 32];
  __shared__ half_t Bs[128 * 32];
  __shared__ float red[4];

  const int t = threadIdx.x;
  const int lane = t & 63;
  const int w = t >> 6;
  const int m0 = blockIdx.x * 128;
  const int n0 = blockIdx.y * 128;
  const int k0 = blockIdx.z * 1024;

  // staging: each wave-instr covers 16 rows x 64B; lane i -> row i/4, 16B chunk i%4
  const int srow = w * 16 + (lane >> 2);
  const int schunk = (lane & 3) * 8;  // halfs
  const half_t* gA = At + (size_t)(n0 + srow) * KTOT + k0 + schunk;
  const half_t* gB = Bt + (size_t)(m0 + srow) * KTOT + k0 + schunk;
  half_t* lA = As + (size_t)(w * 16) * 32;  // wave-uniform LDS base
  half_t* lB = Bs + (size_t)(w * 16) * 32;

  const int wm = (w & 1) * 64;   // n-dim wave offset
  const int wn = (w >> 1) * 64;  // m-dim wave offset
  const int fra = wm + (lane & 15);
  const int frb = wn + (lane & 15);
  const int fk = (lane >> 4) * 8;

  f32x4 acc[4][4] = {};

  for (int kt = 0; kt < 32; ++kt) {
    const half_t* ga = gA + kt * 32;
    const half_t* gb = gB + kt * 32;
    __builtin_amdgcn_global_load_lds((const GLOBAL_AS void*)ga,              (LDS_AS void*)lA,             16, 0, 0);
    __builtin_amdgcn_global_load_lds((const GLOBAL_AS void*)(ga + 64 * KTOT),(LDS_AS void*)(lA + 64 * 32), 16, 0, 0);
    __builtin_amdgcn_global_load_lds((const GLOBAL_AS void*)gb,              (LDS_AS void*)lB,             16, 0, 0);
    __builtin_amdgcn_global_load_lds((const GLOBAL_AS void*)(gb + 64 * KTOT),(LDS_AS void*)(lB + 64 * 32), 16, 0, 0);
    __syncthreads();
    f16x8 af[4], bf[4];
#pragma unroll
    for (int i = 0; i < 4; ++i) af[i] = *(const f16x8*)(As + (fra + i * 16) * 32 + fk);
#pragma unroll
    for (int j = 0; j < 4; ++j) bf[j] = *(const f16x8*)(Bs + (frb + j * 16) * 32 + fk);
#pragma unroll
    for (int i = 0; i < 4; ++i)
#pragma unroll
      for (int j = 0; j < 4; ++j)
        acc[i][j] = __builtin_amdgcn_mfma_f32_16x16x32_f16(af[i], bf[j], acc[i][j], 0, 0, 0);
    __syncthreads();
  }

  // masked-sum epilogue; C/D layout: col = lane&15 (m), row = (lane>>4)*4 + reg (n)
  float local = 0.f;
#pragma unroll
  for (int i = 0; i < 4; ++i) {
    const int ng = n0 + wm + i * 16 + (lane >> 4) * 4;
#pragma unroll
    for (int j = 0; j < 4; ++j) {
      const int mg = m0 + wn + j * 16 + (lane & 15);
      const float* dp = dist + (size_t)ng * N + mg;
#pragma unroll
      for (int r = 0; r < 4; ++r) {
        if (dp[(size_t)r * N] < THR) local += acc[i][j][r];
      }
    }
  }
#pragma unroll
  for (int off = 32; off; off >>= 1) local += __shfl_down(local, off, 64);
  if (lane == 0) red[w] = local;
  __syncthreads();
  if (t == 0) atomicAdd(s_out, red[0] + red[1] + red[2] + red[3]);
}

// ---------------- 5. finalize ----------------
__global__ void finalize_kernel(const float* __restrict__ s, const unsigned int* __restrict__ cnt,
                                float* __restrict__ out) {
  out[0] = -s[0] / ((float)cnt[0] * (float)BATCH);
}

extern "C" void kernel_launch(void* const* d_in, const int* in_sizes, int n_in,
                              void* d_out, int out_size, void* d_ws, size_t ws_size,
                              hipStream_t stream) {
  const float* y    = (const float*)d_in[0];
  const float* yp   = (const float*)d_in[1];
  const float* z    = (const float*)d_in[2];
  const float* zp   = (const float*)d_in[3];
  const float* dist = (const float*)d_in[4];
  float* out = (float*)d_out;

  char* ws = (char*)d_ws;
  float* s_acc = (float*)ws;
  unsigned int* cnt = (unsigned int*)(ws + 4);
  float* scales = (float*)(ws + 256);
  half_t* At = (half_t*)(ws + 295168);
  half_t* Bt = (half_t*)(ws + 295168 + 18874368);

  hipMemsetAsync(ws, 0, 16, stream);
  norms_kernel<<<dim3(9, 8, 4), 256, 0, stream>>>(y, yp, z, zp, scales);
  pack_kernel<<<dim3(36, 32, 4), 256, 0, stream>>>(y, yp, z, zp, scales, At, Bt);
  count_kernel<<<2592, 256, 0, stream>>>(dist, cnt);
  gemm_kernel<<<dim3(18, 18, 4), 256, 0, stream>>>(At, Bt, dist, s_acc);
  finalize_kernel<<<1, 1, 0, stream>>>(s_acc, cnt, out);
}

// Round 2
// 219.782 us; speedup vs baseline: 1.2075x; 1.2075x over previous
//
#include <hip/hip_runtime.h>
#include <stdint.h>

#define GLOBAL_AS __attribute__((address_space(1)))
#define LDS_AS __attribute__((address_space(3)))

typedef _Float16 half_t;
typedef _Float16 f16x8 __attribute__((ext_vector_type(8)));
typedef float f32x4 __attribute__((ext_vector_type(4)));

static constexpr int BATCH = 8;
static constexpr int CH = 256;
static constexpr int N = 2304;     // 48*48
static constexpr int KTOT = 4096;  // 2 * BATCH * CH (G1 and G2 fused along K)
static constexpr int MW = 72;      // mask words per row (2304/32)
static constexpr float EPS = 1e-8f;
static constexpr float THR = 31.5f;

// ws layout:
//   [0,4)    float s accumulator   [4,8) uint mask count
//   [256, +294912)   float scales[4][8][2304]
//   At = ws + 295168          : half [2304][4096] rows=n, k-contig ([yhat; zhat])
//   Bt = At + 18874368 B      : half [2304][4096] rows=m, k-contig ([zphat; yphat])
//   maskw = ws + 38043904     : uint32 [2304][72] bitmask of (dist < THR)
// total ~38.7 MB

// ---------------- 1. per-(tensor,b,n) inverse norms (1024 thr, LDS reduce) ----
__global__ __launch_bounds__(1024) void norms_kernel(
    const float* __restrict__ y, const float* __restrict__ yp,
    const float* __restrict__ z, const float* __restrict__ zp,
    float* __restrict__ scales) {
  const int t = threadIdx.x;
  const int nn = t & 255, cg = t >> 8;        // 4 c-groups of 64
  const int n0 = blockIdx.x * 256;            // 9 * 256 = 2304
  const int b = blockIdx.y;
  const int tz = blockIdx.z;
  const float* src = (tz == 0) ? y : (tz == 1) ? yp : (tz == 2) ? z : zp;
  const float* p = src + (size_t)(b * CH + cg * 64) * N + n0 + nn;
  float ss = 0.f;
#pragma unroll 8
  for (int c = 0; c < 64; ++c) {
    float v = p[(size_t)c * N];
    ss = fmaf(v, v, ss);
  }
  __shared__ float partial[4][256];
  partial[cg][nn] = ss;
  __syncthreads();
  if (t < 256) {
    float s = partial[0][t] + partial[1][t] + partial[2][t] + partial[3][t];
    scales[((size_t)tz * BATCH + b) * N + n0 + t] = 1.0f / fmaxf(sqrtf(s), EPS);
  }
}

// ---------------- 2. normalize + transpose to [n][k] fp16 ----------------
// bz: 0: y -> At k<2048 | 1: z -> At k>=2048 | 2: zp -> Bt k<2048 | 3: yp -> Bt k>=2048
__global__ void pack_kernel(const float* __restrict__ y, const float* __restrict__ yp,
                            const float* __restrict__ z, const float* __restrict__ zp,
                            const float* __restrict__ scales,
                            half_t* __restrict__ At, half_t* __restrict__ Bt) {
  const int bz = blockIdx.z;
  const int b  = blockIdx.y >> 2;
  const int ct = blockIdx.y & 3;   // 64-wide c tile
  const int n0 = blockIdx.x * 64;  // 36*64 = 2304
  const float* src; int sidx; half_t* dst;
  switch (bz) {
    case 0:  src = y;  sidx = 0; dst = At; break;
    case 1:  src = z;  sidx = 2; dst = At; break;
    case 2:  src = zp; sidx = 3; dst = Bt; break;
    default: src = yp; sidx = 1; dst = Bt; break;
  }
  const int kb = ((bz & 1) ? 2048 : 0) + b * 256 + ct * 64;

  __shared__ float tile[64][65];  // [c][n], +1 pad
  const int t = threadIdx.x;
  {
    const int col = (t & 15) * 4;
    const int cb  = t >> 4;
#pragma unroll
    for (int r = 0; r < 4; ++r) {
      const int cc = r * 16 + cb;
      const float4 v = *(const float4*)(src + (size_t)(b * CH + ct * 64 + cc) * N + n0 + col);
      tile[cc][col] = v.x; tile[cc][col + 1] = v.y;
      tile[cc][col + 2] = v.z; tile[cc][col + 3] = v.w;
    }
  }
  __syncthreads();
  const int nn = t >> 2, cseg = t & 3;
  const float sc = scales[((size_t)sidx * BATCH + b) * N + n0 + nn];
  union { half_t h[16]; f16x8 v[2]; } u;
#pragma unroll
  for (int i = 0; i < 16; ++i)
    u.h[i] = (half_t)(tile[cseg * 16 + i][nn] * sc);
  f16x8* dp = (f16x8*)(dst + (size_t)(n0 + nn) * KTOT + kb + cseg * 16);
  dp[0] = u.v[0];
  dp[1] = u.v[1];
}

// ---------------- 3. bitmask build + count ----------------
__global__ void mask_kernel(const float* __restrict__ dist,
                            uint32_t* __restrict__ words, unsigned int* __restrict__ cnt) {
  const int w = blockIdx.x * 256 + threadIdx.x;  // 648*256 = 165888 = 2304*72
  const float4* p = (const float4*)(dist + (size_t)w * 32);
  uint32_t bits = 0;
#pragma unroll
  for (int q = 0; q < 8; ++q) {
    float4 v = p[q];
    bits |= (v.x < THR ? 1u : 0u) << (q * 4);
    bits |= (v.y < THR ? 1u : 0u) << (q * 4 + 1);
    bits |= (v.z < THR ? 1u : 0u) << (q * 4 + 2);
    bits |= (v.w < THR ? 1u : 0u) << (q * 4 + 3);
  }
  words[w] = bits;
  int c = __popc(bits);
#pragma unroll
  for (int off = 32; off; off >>= 1) c += __shfl_down(c, off, 64);
  __shared__ int red[4];
  if ((threadIdx.x & 63) == 0) red[threadIdx.x >> 6] = c;
  __syncthreads();
  if (threadIdx.x == 0)
    atomicAdd(cnt, (unsigned int)(red[0] + red[1] + red[2] + red[3]));
}

// ---------------- 4. GEMM s += sum_mask (At * Bt^T) ----------------
// 128x128 tile, BK=32, K-split z=4. LDS XOR-swizzled: slot (row, c') holds
// global chunk c' ^ ((row>>1)&3) -> ds_read_b128 frag reads are 2-way (free).
__global__ __launch_bounds__(256) void gemm_kernel(
    const half_t* __restrict__ At, const half_t* __restrict__ Bt,
    const uint32_t* __restrict__ maskw, float* __restrict__ s_out) {
  __shared__ half_t As[128 * 32];
  __shared__ half_t Bs[128 * 32];
  __shared__ float red[4];

  const int t = threadIdx.x;
  const int lane = t & 63;
  const int w = t >> 6;
  const int m0 = blockIdx.x * 128;
  const int n0 = blockIdx.y * 128;
  const int k0 = blockIdx.z * 1024;

  // staging: lane -> LDS slot (row = lane>>2, chunk = lane&3); fetch the global
  // chunk that belongs at this slot under the XOR swizzle: g = (lane&3)^f(row),
  // f(row) = (row>>1)&3 = (lane>>3)&3 here.
  const int srow = w * 16 + (lane >> 2);
  const int schunk = ((lane & 3) ^ ((lane >> 3) & 3)) * 8;  // halfs
  const half_t* gA = At + (size_t)(n0 + srow) * KTOT + k0 + schunk;
  const half_t* gB = Bt + (size_t)(m0 + srow) * KTOT + k0 + schunk;
  half_t* lA = As + (size_t)(w * 16) * 32;  // wave-uniform LDS base
  half_t* lB = Bs + (size_t)(w * 16) * 32;

  const int wm = (w & 1) * 64;   // n-dim wave offset
  const int wn = (w >> 1) * 64;  // m-dim wave offset
  const int fra = wm + (lane & 15);
  const int frb = wn + (lane & 15);
  // swizzled k-chunk for frag reads: want global chunk lane>>4 at row with
  // f(row) = ((lane&15)>>1)&3 = (lane>>1)&3
  const int fk = ((lane >> 4) ^ ((lane >> 1) & 3)) * 8;

  f32x4 acc[4][4] = {};

  for (int kt = 0; kt < 32; ++kt) {
    const half_t* ga = gA + kt * 32;
    const half_t* gb = gB + kt * 32;
    __builtin_amdgcn_global_load_lds((const GLOBAL_AS void*)ga,               (LDS_AS void*)lA,             16, 0, 0);
    __builtin_amdgcn_global_load_lds((const GLOBAL_AS void*)(ga + 64 * KTOT), (LDS_AS void*)(lA + 64 * 32), 16, 0, 0);
    __builtin_amdgcn_global_load_lds((const GLOBAL_AS void*)gb,               (LDS_AS void*)lB,             16, 0, 0);
    __builtin_amdgcn_global_load_lds((const GLOBAL_AS void*)(gb + 64 * KTOT), (LDS_AS void*)(lB + 64 * 32), 16, 0, 0);
    __syncthreads();
    f16x8 af[4], bf[4];
#pragma unroll
    for (int i = 0; i < 4; ++i) af[i] = *(const f16x8*)(As + (fra + i * 16) * 32 + fk);
#pragma unroll
    for (int j = 0; j < 4; ++j) bf[j] = *(const f16x8*)(Bs + (frb + j * 16) * 32 + fk);
#pragma unroll
    for (int i = 0; i < 4; ++i)
#pragma unroll
      for (int j = 0; j < 4; ++j)
        acc[i][j] = __builtin_amdgcn_mfma_f32_16x16x32_f16(af[i], bf[j], acc[i][j], 0, 0, 0);
    __syncthreads();
  }

  // masked-sum epilogue via bitmask; C/D: col = lane&15 (m), row = (lane>>4)*4+reg (n)
  // m0+wn is 32-aligned: j=0,1 share word mbase, j=2,3 share mbase+1.
  float local = 0.f;
  const int mbase = (m0 + wn) >> 5;
  const int mbit = lane & 15;
#pragma unroll
  for (int i = 0; i < 4; ++i) {
    const int ng = n0 + wm + i * 16 + (lane >> 4) * 4;
#pragma unroll
    for (int r = 0; r < 4; ++r) {
      const uint32_t* rw = maskw + (size_t)(ng + r) * MW + mbase;
      const uint32_t w0 = rw[0], w1 = rw[1];
      if ((w0 >> mbit) & 1u)        local += acc[0][0][r] * 0.f + acc[i][0][r];
      if ((w0 >> (mbit + 16)) & 1u) local += acc[i][1][r];
      if ((w1 >> mbit) & 1u)        local += acc[i][2][r];
      if ((w1 >> (mbit + 16)) & 1u) local += acc[i][3][r];
    }
  }
#pragma unroll
  for (int off = 32; off; off >>= 1) local += __shfl_down(local, off, 64);
  if (lane == 0) red[w] = local;
  __syncthreads();
  if (t == 0) atomicAdd(s_out, red[0] + red[1] + red[2] + red[3]);
}

// ---------------- 5. finalize ----------------
__global__ void finalize_kernel(const float* __restrict__ s, const unsigned int* __restrict__ cnt,
                                float* __restrict__ out) {
  out[0] = -s[0] / ((float)cnt[0] * (float)BATCH);
}

extern "C" void kernel_launch(void* const* d_in, const int* in_sizes, int n_in,
                              void* d_out, int out_size, void* d_ws, size_t ws_size,
                              hipStream_t stream) {
  const float* y    = (const float*)d_in[0];
  const float* yp   = (const float*)d_in[1];
  const float* z    = (const float*)d_in[2];
  const float* zp   = (const float*)d_in[3];
  const float* dist = (const float*)d_in[4];
  float* out = (float*)d_out;

  char* ws = (char*)d_ws;
  float* s_acc = (float*)ws;
  unsigned int* cnt = (unsigned int*)(ws + 4);
  float* scales = (float*)(ws + 256);
  half_t* At = (half_t*)(ws + 295168);
  half_t* Bt = (half_t*)(ws + 295168 + 18874368);
  uint32_t* maskw = (uint32_t*)(ws + 38043904);

  hipMemsetAsync(ws, 0, 16, stream);
  norms_kernel<<<dim3(9, 8, 4), 1024, 0, stream>>>(y, yp, z, zp, scales);
  pack_kernel<<<dim3(36, 32, 4), 256, 0, stream>>>(y, yp, z, zp, scales, At, Bt);
  mask_kernel<<<648, 256, 0, stream>>>(dist, maskw, cnt);
  gemm_kernel<<<dim3(18, 18, 4), 256, 0, stream>>>(At, Bt, maskw, s_acc);
  finalize_kernel<<<1, 1, 0, stream>>>(s_acc, cnt, out);
}

// Round 3
// 216.605 us; speedup vs baseline: 1.2252x; 1.0147x over previous
//
#include <hip/hip_runtime.h>
#include <stdint.h>

#define GLOBAL_AS __attribute__((address_space(1)))
#define LDS_AS __attribute__((address_space(3)))

typedef _Float16 half_t;
typedef _Float16 f16x8 __attribute__((ext_vector_type(8)));
typedef float f32x4 __attribute__((ext_vector_type(4)));

static constexpr int BATCH = 8;
static constexpr int CH = 256;
static constexpr int N = 2304;     // 48*48
static constexpr int KTOT = 4096;  // 2 * BATCH * CH (G1 and G2 fused along K)
static constexpr int MW = 72;      // mask words per row (2304/32)
static constexpr float EPS = 1e-8f;
static constexpr float THR = 31.5f;

// ws layout:
//   [0,4)  float s accumulator    [4,8) uint mask count
//   At = ws + 256             : half [2304][4096] rows=n, k-contig ([yhat; zhat])
//   Bt = At + 18874368 B      : half [2304][4096] rows=m, k-contig ([zphat; yphat])
//   maskw = Bt + 18874368 B   : uint32 [2304][72] bitmask of (dist < THR)
// total ~38.4 MB

// ---------------- 1. fused norm + normalize + transpose-pack --------------
// One block = (tensor, batch, 64-wide n tile); stages all 256 channels in
// LDS fp32, computes 1/||x|| in-block, writes normalized fp16 k-contig.
// blockIdx.z: 0: y->At k<2048 | 1: z->At k>=2048 | 2: zp->Bt k<2048 | 3: yp->Bt k>=2048
__global__ __launch_bounds__(256) void pack_kernel(
    const float* __restrict__ y, const float* __restrict__ yp,
    const float* __restrict__ z, const float* __restrict__ zp,
    half_t* __restrict__ At, half_t* __restrict__ Bt) {
  const int bz = blockIdx.z;
  const int b  = blockIdx.y;
  const int n0 = blockIdx.x * 64;  // 36*64 = 2304
  const float* src; half_t* dst;
  switch (bz) {
    case 0:  src = y;  dst = At; break;
    case 1:  src = z;  dst = At; break;
    case 2:  src = zp; dst = Bt; break;
    default: src = yp; dst = Bt; break;
  }
  const int kbase = ((bz & 1) ? 2048 : 0) + b * 256;

  __shared__ float tile[4][64][65];  // [c-chunk][c][n], +1 pad
  __shared__ float ssp[64][4];
  __shared__ float sc[64];

  const int t = threadIdx.x;
  // ---- stage A: global -> LDS (proven-coalesced: 16 lanes x 16B per row) ----
  {
    const int col = (t & 15) * 4;
    const int cb  = t >> 4;  // 0..15 -> (ch = cb>>2, r... ) use: 16 rows per (ch)
    float4 v[4];
#pragma unroll
    for (int ch = 0; ch < 4; ++ch) {
      const int cc = ch * 64 + (cb & 3) * 16 + (cb >> 2);  // spread rows
#pragma unroll
      for (int r = 0; r < 1; ++r) {}
      v[ch] = *(const float4*)(src + (size_t)(b * CH + cc) * N + n0 + col);
    }
    // second set: each thread loads 4 more rows (total 16 rows/thread-group)
    float4 v2[4];
#pragma unroll
    for (int ch = 0; ch < 4; ++ch) {
      const int cc = ch * 64 + (cb & 3) * 16 + (cb >> 2) + 4;
      v2[ch] = *(const float4*)(src + (size_t)(b * CH + cc) * N + n0 + col);
    }
    float4 v3[4], v4[4];
#pragma unroll
    for (int ch = 0; ch < 4; ++ch) {
      const int cc = ch * 64 + (cb & 3) * 16 + (cb >> 2) + 8;
      v3[ch] = *(const float4*)(src + (size_t)(b * CH + cc) * N + n0 + col);
    }
#pragma unroll
    for (int ch = 0; ch < 4; ++ch) {
      const int cc = ch * 64 + (cb & 3) * 16 + (cb >> 2) + 12;
      v4[ch] = *(const float4*)(src + (size_t)(b * CH + cc) * N + n0 + col);
    }
#pragma unroll
    for (int ch = 0; ch < 4; ++ch) {
      const int c0 = (cb & 3) * 16 + (cb >> 2);
      float* d0 = &tile[ch][c0][col];
      d0[0] = v[ch].x; d0[1] = v[ch].y; d0[2] = v[ch].z; d0[3] = v[ch].w;
      float* d1 = &tile[ch][c0 + 4][col];
      d1[0] = v2[ch].x; d1[1] = v2[ch].y; d1[2] = v2[ch].z; d1[3] = v2[ch].w;
      float* d2 = &tile[ch][c0 + 8][col];
      d2[0] = v3[ch].x; d2[1] = v3[ch].y; d2[2] = v3[ch].z; d2[3] = v3[ch].w;
      float* d3 = &tile[ch][c0 + 12][col];
      d3[0] = v4[ch].x; d3[1] = v4[ch].y; d3[2] = v4[ch].z; d3[3] = v4[ch].w;
    }
  }
  __syncthreads();

  // ---- stage B: per-n sum of squares (fp32, pre-rounding) ----
  const int nn = t >> 2, cseg = t & 3;
  {
    float ss = 0.f;
#pragma unroll
    for (int ch = 0; ch < 4; ++ch)
#pragma unroll
      for (int i = 0; i < 16; ++i) {
        float v = tile[ch][cseg * 16 + i][nn];
        ss = fmaf(v, v, ss);
      }
    ssp[nn][cseg] = ss;
  }
  __syncthreads();
  if (t < 64) {
    float s = ssp[t][0] + ssp[t][1] + ssp[t][2] + ssp[t][3];
    sc[t] = 1.0f / fmaxf(sqrtf(s), EPS);
  }
  __syncthreads();

  // ---- stage C: normalize, cvt fp16, write k-contiguous ----
  {
    const float scale = sc[nn];
#pragma unroll
    for (int ch = 0; ch < 4; ++ch) {
      union { half_t h[16]; f16x8 v[2]; } u;
#pragma unroll
      for (int i = 0; i < 16; ++i)
        u.h[i] = (half_t)(tile[ch][cseg * 16 + i][nn] * scale);
      f16x8* dp = (f16x8*)(dst + (size_t)(n0 + nn) * KTOT + kbase + ch * 64 + cseg * 16);
      dp[0] = u.v[0];
      dp[1] = u.v[1];
    }
  }
}

// ---------------- 2. bitmask build + count ----------------
__global__ void mask_kernel(const float* __restrict__ dist,
                            uint32_t* __restrict__ words, unsigned int* __restrict__ cnt) {
  const int w = blockIdx.x * 256 + threadIdx.x;  // 648*256 = 165888 = 2304*72
  const float4* p = (const float4*)(dist + (size_t)w * 32);
  uint32_t bits = 0;
#pragma unroll
  for (int q = 0; q < 8; ++q) {
    float4 v = p[q];
    bits |= (v.x < THR ? 1u : 0u) << (q * 4);
    bits |= (v.y < THR ? 1u : 0u) << (q * 4 + 1);
    bits |= (v.z < THR ? 1u : 0u) << (q * 4 + 2);
    bits |= (v.w < THR ? 1u : 0u) << (q * 4 + 3);
  }
  words[w] = bits;
  int c = __popc(bits);
#pragma unroll
  for (int off = 32; off; off >>= 1) c += __shfl_down(c, off, 64);
  __shared__ int red[4];
  if ((threadIdx.x & 63) == 0) red[threadIdx.x >> 6] = c;
  __syncthreads();
  if (threadIdx.x == 0)
    atomicAdd(cnt, (unsigned int)(red[0] + red[1] + red[2] + red[3]));
}

// ---------------- 3. GEMM s += sum_mask (At * Bt^T) ----------------
// 128x128 tile, BK=32, K-split z=8 (2592 blocks -> ~6 resident blocks/CU).
// LDS XOR-swizzled: slot (row, c') holds global chunk c' ^ ((row>>1)&3).
__global__ __launch_bounds__(256) void gemm_kernel(
    const half_t* __restrict__ At, const half_t* __restrict__ Bt,
    const uint32_t* __restrict__ maskw, float* __restrict__ s_out) {
  __shared__ half_t As[128 * 32];
  __shared__ half_t Bs[128 * 32];
  __shared__ float red[4];

  const int t = threadIdx.x;
  const int lane = t & 63;
  const int w = t >> 6;
  const int m0 = blockIdx.x * 128;
  const int n0 = blockIdx.y * 128;
  const int k0 = blockIdx.z * 512;

  const int srow = w * 16 + (lane >> 2);
  const int schunk = ((lane & 3) ^ ((lane >> 3) & 3)) * 8;  // halfs
  const half_t* gA = At + (size_t)(n0 + srow) * KTOT + k0 + schunk;
  const half_t* gB = Bt + (size_t)(m0 + srow) * KTOT + k0 + schunk;
  half_t* lA = As + (size_t)(w * 16) * 32;  // wave-uniform LDS base
  half_t* lB = Bs + (size_t)(w * 16) * 32;

  const int wm = (w & 1) * 64;   // n-dim wave offset
  const int wn = (w >> 1) * 64;  // m-dim wave offset
  const int fra = wm + (lane & 15);
  const int frb = wn + (lane & 15);
  const int fk = ((lane >> 4) ^ ((lane >> 1) & 3)) * 8;

  f32x4 acc[4][4] = {};

  for (int kt = 0; kt < 16; ++kt) {
    const half_t* ga = gA + kt * 32;
    const half_t* gb = gB + kt * 32;
    __builtin_amdgcn_global_load_lds((const GLOBAL_AS void*)ga,               (LDS_AS void*)lA,             16, 0, 0);
    __builtin_amdgcn_global_load_lds((const GLOBAL_AS void*)(ga + 64 * KTOT), (LDS_AS void*)(lA + 64 * 32), 16, 0, 0);
    __builtin_amdgcn_global_load_lds((const GLOBAL_AS void*)gb,               (LDS_AS void*)lB,             16, 0, 0);
    __builtin_amdgcn_global_load_lds((const GLOBAL_AS void*)(gb + 64 * KTOT), (LDS_AS void*)(lB + 64 * 32), 16, 0, 0);
    __syncthreads();
    f16x8 af[4], bf[4];
#pragma unroll
    for (int i = 0; i < 4; ++i) af[i] = *(const f16x8*)(As + (fra + i * 16) * 32 + fk);
#pragma unroll
    for (int j = 0; j < 4; ++j) bf[j] = *(const f16x8*)(Bs + (frb + j * 16) * 32 + fk);
#pragma unroll
    for (int i = 0; i < 4; ++i)
#pragma unroll
      for (int j = 0; j < 4; ++j)
        acc[i][j] = __builtin_amdgcn_mfma_f32_16x16x32_f16(af[i], bf[j], acc[i][j], 0, 0, 0);
    __syncthreads();
  }

  // masked-sum epilogue via bitmask; C/D: col = lane&15 (m), row = (lane>>4)*4+reg (n)
  float local = 0.f;
  const int mbase = (m0 + wn) >> 5;
  const int mbit = lane & 15;
#pragma unroll
  for (int i = 0; i < 4; ++i) {
    const int ng = n0 + wm + i * 16 + (lane >> 4) * 4;
#pragma unroll
    for (int r = 0; r < 4; ++r) {
      const uint32_t* rw = maskw + (size_t)(ng + r) * MW + mbase;
      const uint32_t w0 = rw[0], w1 = rw[1];
      if ((w0 >> mbit) & 1u)        local += acc[i][0][r];
      if ((w0 >> (mbit + 16)) & 1u) local += acc[i][1][r];
      if ((w1 >> mbit) & 1u)        local += acc[i][2][r];
      if ((w1 >> (mbit + 16)) & 1u) local += acc[i][3][r];
    }
  }
#pragma unroll
  for (int off = 32; off; off >>= 1) local += __shfl_down(local, off, 64);
  if (lane == 0) red[w] = local;
  __syncthreads();
  if (t == 0) atomicAdd(s_out, red[0] + red[1] + red[2] + red[3]);
}

// ---------------- 4. finalize ----------------
__global__ void finalize_kernel(const float* __restrict__ s, const unsigned int* __restrict__ cnt,
                                float* __restrict__ out) {
  out[0] = -s[0] / ((float)cnt[0] * (float)BATCH);
}

extern "C" void kernel_launch(void* const* d_in, const int* in_sizes, int n_in,
                              void* d_out, int out_size, void* d_ws, size_t ws_size,
                              hipStream_t stream) {
  const float* y    = (const float*)d_in[0];
  const float* yp   = (const float*)d_in[1];
  const float* z    = (const float*)d_in[2];
  const float* zp   = (const float*)d_in[3];
  const float* dist = (const float*)d_in[4];
  float* out = (float*)d_out;

  char* ws = (char*)d_ws;
  float* s_acc = (float*)ws;
  unsigned int* cnt = (unsigned int*)(ws + 4);
  half_t* At = (half_t*)(ws + 256);
  half_t* Bt = (half_t*)(ws + 256 + 18874368);
  uint32_t* maskw = (uint32_t*)(ws + 256 + 2 * 18874368);

  hipMemsetAsync(ws, 0, 16, stream);
  pack_kernel<<<dim3(36, 8, 4), 256, 0, stream>>>(y, yp, z, zp, At, Bt);
  mask_kernel<<<648, 256, 0, stream>>>(dist, maskw, cnt);
  gemm_kernel<<<dim3(18, 18, 8), 256, 0, stream>>>(At, Bt, maskw, s_acc);
  finalize_kernel<<<1, 1, 0, stream>>>(s_acc, cnt, out);
}

// Round 4
// 192.156 us; speedup vs baseline: 1.3811x; 1.1272x over previous
//
#include <hip/hip_runtime.h>
#include <stdint.h>

#define GLOBAL_AS __attribute__((address_space(1)))
#define LDS_AS __attribute__((address_space(3)))

typedef _Float16 half_t;
typedef _Float16 f16x8 __attribute__((ext_vector_type(8)));
typedef float f32x4 __attribute__((ext_vector_type(4)));

static constexpr int BATCH = 8;
static constexpr int CH = 256;
static constexpr int N = 2304;     // 48*48
static constexpr int KTOT = 4096;  // 2 * BATCH * CH (G1 and G2 fused along K)
static constexpr int MW = 72;      // mask words per row (2304/32)
static constexpr int MWORDS = 165888;  // 2304*72
static constexpr float EPS = 1e-8f;
static constexpr float THR = 31.5f;

// ws layout:
//   [0,4)   uint mask count
//   [64, +5184)  float s_part[1296]  (per-gemm-block partials)
//   At = ws + 8192            : half [2304][4096] rows=n, k-contig ([yhat; zhat])
//   Bt = At + 18874368 B      : half [2304][4096] rows=m, k-contig ([zphat; yphat])
//   maskw = Bt + 18874368 B   : uint32 [2304][72] bitmask of (dist < THR)
// total ~36.6 MB

// ------------- 1. prep: fused norm+pack (z<4) and mask build (z>=4) -------------
// Pack path: block = (tensor, batch, 64-n tile). Thread t owns 4 columns
// (n = n0 + (t&15)*4 + j) and one 16-channel k-chunk (cb = t>>4). The 16
// strided float4 loads land the thread's data k-contiguously in REGISTERS;
// only the 256-channel sumsq reduce goes through LDS (4 KB).
__global__ __launch_bounds__(256) void prep_kernel(
    const float* __restrict__ y, const float* __restrict__ yp,
    const float* __restrict__ z, const float* __restrict__ zp,
    const float* __restrict__ dist,
    half_t* __restrict__ At, half_t* __restrict__ Bt,
    uint32_t* __restrict__ maskw, unsigned int* __restrict__ cnt) {
  const int t = threadIdx.x;
  const int bz = blockIdx.z;

  if (bz >= 4) {
    // ---- mask path: 3*8*36 = 864 blocks cover 165888 words ----
    const int blk = ((bz - 4) * 8 + blockIdx.y) * 36 + blockIdx.x;
    const int w = blk * 256 + t;
    int c = 0;
    if (w < MWORDS) {
      const float4* p = (const float4*)(dist + (size_t)w * 32);
      uint32_t bits = 0;
#pragma unroll
      for (int q = 0; q < 8; ++q) {
        float4 v = p[q];
        bits |= (v.x < THR ? 1u : 0u) << (q * 4);
        bits |= (v.y < THR ? 1u : 0u) << (q * 4 + 1);
        bits |= (v.z < THR ? 1u : 0u) << (q * 4 + 2);
        bits |= (v.w < THR ? 1u : 0u) << (q * 4 + 3);
      }
      maskw[w] = bits;
      c = __popc(bits);
    }
#pragma unroll
    for (int off = 32; off; off >>= 1) c += __shfl_down(c, off, 64);
    __shared__ int mred[4];
    if ((t & 63) == 0) mred[t >> 6] = c;
    __syncthreads();
    if (t == 0)
      atomicAdd(cnt, (unsigned int)(mred[0] + mred[1] + mred[2] + mred[3]));
    return;
  }

  // ---- pack path ----
  const int b = blockIdx.y;
  const int n0 = blockIdx.x * 64;  // 36*64 = 2304
  const float* src; half_t* dst; int kh;
  switch (bz) {
    case 0:  src = y;  dst = At; kh = 0;    break;
    case 1:  src = z;  dst = At; kh = 2048; break;
    case 2:  src = zp; dst = Bt; kh = 0;    break;
    default: src = yp; dst = Bt; kh = 2048; break;
  }
  const int kbase = kh + b * 256;
  const int col4 = (t & 15) * 4;   // n offset within tile
  const int cb = t >> 4;           // 16-channel k-chunk

  const float* base = src + (size_t)(b * CH + cb * 16) * N + n0 + col4;
  float4 v[16];
#pragma unroll
  for (int i = 0; i < 16; ++i) v[i] = *(const float4*)(base + (size_t)i * N);

  float ss[4] = {0.f, 0.f, 0.f, 0.f};
#pragma unroll
  for (int i = 0; i < 16; ++i) {
    ss[0] = fmaf(v[i].x, v[i].x, ss[0]);
    ss[1] = fmaf(v[i].y, v[i].y, ss[1]);
    ss[2] = fmaf(v[i].z, v[i].z, ss[2]);
    ss[3] = fmaf(v[i].w, v[i].w, ss[3]);
  }
  __shared__ float partial[16][65];  // [cb][n], 65-stride -> 2-way banks (free)
  __shared__ float sc[64];
#pragma unroll
  for (int j = 0; j < 4; ++j) partial[cb][col4 + j] = ss[j];
  __syncthreads();
  if (t < 64) {
    float s = 0.f;
#pragma unroll
    for (int k = 0; k < 16; ++k) s += partial[k][t];
    sc[t] = 1.0f / fmaxf(sqrtf(s), EPS);
  }
  __syncthreads();

#pragma unroll
  for (int j = 0; j < 4; ++j) {
    const float scj = sc[col4 + j];
    union { half_t h[16]; f16x8 v2[2]; } u;
#pragma unroll
    for (int i = 0; i < 16; ++i)
      u.h[i] = (half_t)(((const float*)&v[i])[j] * scj);
    f16x8* q = (f16x8*)(dst + (size_t)(n0 + col4 + j) * KTOT + kbase + cb * 16);
    q[0] = u.v2[0];
    q[1] = u.v2[1];
  }
}

// ---------------- 2. GEMM s_part[bid] = sum_mask (At * Bt^T) tile ----------------
// 128x128 tile, BK=32, K-split z=4 (1296 blocks). LDS XOR-swizzled:
// slot (row, c') holds global chunk c' ^ ((row>>1)&3) -> all LDS ops 2-way (free).
__global__ __launch_bounds__(256) void gemm_kernel(
    const half_t* __restrict__ At, const half_t* __restrict__ Bt,
    const uint32_t* __restrict__ maskw, float* __restrict__ s_part) {
  __shared__ half_t As[128 * 32];
  __shared__ half_t Bs[128 * 32];
  __shared__ float red[4];

  const int t = threadIdx.x;
  const int lane = t & 63;
  const int w = t >> 6;
  const int m0 = blockIdx.x * 128;
  const int n0 = blockIdx.y * 128;
  const int k0 = blockIdx.z * 1024;

  const int srow = w * 16 + (lane >> 2);
  const int schunk = ((lane & 3) ^ ((lane >> 3) & 3)) * 8;  // halfs
  const half_t* gA = At + (size_t)(n0 + srow) * KTOT + k0 + schunk;
  const half_t* gB = Bt + (size_t)(m0 + srow) * KTOT + k0 + schunk;
  half_t* lA = As + (size_t)(w * 16) * 32;  // wave-uniform LDS base
  half_t* lB = Bs + (size_t)(w * 16) * 32;

  const int wm = (w & 1) * 64;   // n-dim wave offset
  const int wn = (w >> 1) * 64;  // m-dim wave offset
  const int fra = wm + (lane & 15);
  const int frb = wn + (lane & 15);
  const int fk = ((lane >> 4) ^ ((lane >> 1) & 3)) * 8;

  f32x4 acc[4][4] = {};

  for (int kt = 0; kt < 32; ++kt) {
    const half_t* ga = gA + kt * 32;
    const half_t* gb = gB + kt * 32;
    __builtin_amdgcn_global_load_lds((const GLOBAL_AS void*)ga,               (LDS_AS void*)lA,             16, 0, 0);
    __builtin_amdgcn_global_load_lds((const GLOBAL_AS void*)(ga + 64 * KTOT), (LDS_AS void*)(lA + 64 * 32), 16, 0, 0);
    __builtin_amdgcn_global_load_lds((const GLOBAL_AS void*)gb,               (LDS_AS void*)lB,             16, 0, 0);
    __builtin_amdgcn_global_load_lds((const GLOBAL_AS void*)(gb + 64 * KTOT), (LDS_AS void*)(lB + 64 * 32), 16, 0, 0);
    __syncthreads();
    f16x8 af[4], bf[4];
#pragma unroll
    for (int i = 0; i < 4; ++i) af[i] = *(const f16x8*)(As + (fra + i * 16) * 32 + fk);
#pragma unroll
    for (int j = 0; j < 4; ++j) bf[j] = *(const f16x8*)(Bs + (frb + j * 16) * 32 + fk);
#pragma unroll
    for (int i = 0; i < 4; ++i)
#pragma unroll
      for (int j = 0; j < 4; ++j)
        acc[i][j] = __builtin_amdgcn_mfma_f32_16x16x32_f16(af[i], bf[j], acc[i][j], 0, 0, 0);
    __syncthreads();
  }

  // masked-sum epilogue via bitmask; C/D: col = lane&15 (m), row = (lane>>4)*4+reg (n)
  float local = 0.f;
  const int mbase = (m0 + wn) >> 5;
  const int mbit = lane & 15;
#pragma unroll
  for (int i = 0; i < 4; ++i) {
    const int ng = n0 + wm + i * 16 + (lane >> 4) * 4;
#pragma unroll
    for (int r = 0; r < 4; ++r) {
      const uint32_t* rw = maskw + (size_t)(ng + r) * MW + mbase;
      const uint32_t w0 = rw[0], w1 = rw[1];
      if ((w0 >> mbit) & 1u)        local += acc[i][0][r];
      if ((w0 >> (mbit + 16)) & 1u) local += acc[i][1][r];
      if ((w1 >> mbit) & 1u)        local += acc[i][2][r];
      if ((w1 >> (mbit + 16)) & 1u) local += acc[i][3][r];
    }
  }
#pragma unroll
  for (int off = 32; off; off >>= 1) local += __shfl_down(local, off, 64);
  if (lane == 0) red[w] = local;
  __syncthreads();
  if (t == 0) {
    const int bid = (blockIdx.z * 18 + blockIdx.y) * 18 + blockIdx.x;
    s_part[bid] = red[0] + red[1] + red[2] + red[3];
  }
}

// ---------------- 3. finalize: reduce 1296 partials ----------------
__global__ void finalize_kernel(const float* __restrict__ s_part,
                                const unsigned int* __restrict__ cnt,
                                float* __restrict__ out) {
  const int t = threadIdx.x;
  float local = 0.f;
  for (int i = t; i < 1296; i += 256) local += s_part[i];
#pragma unroll
  for (int off = 32; off; off >>= 1) local += __shfl_down(local, off, 64);
  __shared__ float red[4];
  if ((t & 63) == 0) red[t >> 6] = local;
  __syncthreads();
  if (t == 0)
    out[0] = -(red[0] + red[1] + red[2] + red[3]) / ((float)cnt[0] * (float)BATCH);
}

extern "C" void kernel_launch(void* const* d_in, const int* in_sizes, int n_in,
                              void* d_out, int out_size, void* d_ws, size_t ws_size,
                              hipStream_t stream) {
  const float* y    = (const float*)d_in[0];
  const float* yp   = (const float*)d_in[1];
  const float* z    = (const float*)d_in[2];
  const float* zp   = (const float*)d_in[3];
  const float* dist = (const float*)d_in[4];
  float* out = (float*)d_out;

  char* ws = (char*)d_ws;
  unsigned int* cnt = (unsigned int*)ws;
  float* s_part = (float*)(ws + 64);
  half_t* At = (half_t*)(ws + 8192);
  half_t* Bt = (half_t*)(ws + 8192 + 18874368);
  uint32_t* maskw = (uint32_t*)(ws + 8192 + 2 * 18874368);

  hipMemsetAsync(ws, 0, 16, stream);
  prep_kernel<<<dim3(36, 8, 7), 256, 0, stream>>>(y, yp, z, zp, dist, At, Bt, maskw, cnt);
  gemm_kernel<<<dim3(18, 18, 4), 256, 0, stream>>>(At, Bt, maskw, s_part);
  finalize_kernel<<<1, 256, 0, stream>>>(s_part, cnt, out);
}